// Round 4
// baseline (407.881 us; speedup 1.0000x reference)
//
#include <hip/hip_runtime.h>
#include <hip/hip_bf16.h>

#define FDIM 128
#define BROWS 25     // i1-window rows per bucket (<=32 for 5-bit loc pack)
#define NSUP 4       // i0 superbuckets (G slice = N/4 rows ~ 3.2MB, fits XCD L2)

// ---- bf16 helpers (manual, RNE) ----
static __device__ __forceinline__ unsigned short f2bf(float x) {
    unsigned u = __float_as_uint(x);
    unsigned r = 0x7fffu + ((u >> 16) & 1u);
    return (unsigned short)((u + r) >> 16);
}
static __device__ __forceinline__ float bf_lo(unsigned u) { return __uint_as_float(u << 16); }
static __device__ __forceinline__ float bf_hi(unsigned u) { return __uint_as_float(u & 0xffff0000u); }

// ---- k0: Ws = W + W^T ----
__global__ void make_ws(const float* __restrict__ W, float* __restrict__ Ws) {
    int idx = blockIdx.x * blockDim.x + threadIdx.x;
    int i = idx >> 7, j = idx & 127;
    Ws[idx] = W[i * FDIM + j] + W[j * FDIM + i];
}

// ---- k1: G = F @ Ws (bf16 out) AND Fbf = bf16(F) from the staged tile ----
__global__ __launch_bounds__(256, 2) void gemm_g(
    const float* __restrict__ Fm, const float* __restrict__ Ws,
    unsigned short* __restrict__ Gbf, unsigned short* __restrict__ Fbf, int N) {
    __shared__ float sWs[FDIM * FDIM];
    __shared__ float sF[32][FDIM];

    for (int k = threadIdx.x; k < FDIM * FDIM / 4; k += 256)
        ((float4*)sWs)[k] = ((const float4*)Ws)[k];

    int row0 = blockIdx.x * 32;
    for (int k = threadIdx.x; k < 32 * FDIM / 4; k += 256) {
        int r = k >> 5, c = k & 31;
        int gr = row0 + r;
        float4 v = make_float4(0.f, 0.f, 0.f, 0.f);
        if (gr < N) v = ((const float4*)Fm)[(size_t)gr * (FDIM / 4) + c];
        ((float4*)&sF[r][0])[c] = v;
    }
    __syncthreads();

    for (int k = threadIdx.x; k < 32 * FDIM / 4; k += 256) {
        int r = k >> 5, c = k & 31;
        int gr = row0 + r;
        if (gr < N) {
            float4 v = ((float4*)&sF[r][0])[c];
            ushort4 o;
            o.x = f2bf(v.x); o.y = f2bf(v.y); o.z = f2bf(v.z); o.w = f2bf(v.w);
            *(ushort4*)(Fbf + (size_t)gr * FDIM + c * 4) = o;
        }
    }

    int tx = threadIdx.x & 31;
    int ty = threadIdx.x >> 5;
    int c0 = tx * 4;
    float acc[4][4] = {};

    for (int i = 0; i < FDIM; ++i) {
        float4 w = *(const float4*)&sWs[i * FDIM + c0];
        float f0 = sF[ty * 4 + 0][i];
        float f1 = sF[ty * 4 + 1][i];
        float f2 = sF[ty * 4 + 2][i];
        float f3 = sF[ty * 4 + 3][i];
        acc[0][0] = fmaf(f0, w.x, acc[0][0]); acc[0][1] = fmaf(f0, w.y, acc[0][1]);
        acc[0][2] = fmaf(f0, w.z, acc[0][2]); acc[0][3] = fmaf(f0, w.w, acc[0][3]);
        acc[1][0] = fmaf(f1, w.x, acc[1][0]); acc[1][1] = fmaf(f1, w.y, acc[1][1]);
        acc[1][2] = fmaf(f1, w.z, acc[1][2]); acc[1][3] = fmaf(f1, w.w, acc[1][3]);
        acc[2][0] = fmaf(f2, w.x, acc[2][0]); acc[2][1] = fmaf(f2, w.y, acc[2][1]);
        acc[2][2] = fmaf(f2, w.z, acc[2][2]); acc[2][3] = fmaf(f2, w.w, acc[2][3]);
        acc[3][0] = fmaf(f3, w.x, acc[3][0]); acc[3][1] = fmaf(f3, w.y, acc[3][1]);
        acc[3][2] = fmaf(f3, w.z, acc[3][2]); acc[3][3] = fmaf(f3, w.w, acc[3][3]);
    }

    for (int r = 0; r < 4; ++r) {
        int gr = row0 + ty * 4 + r;
        if (gr < N) {
            ushort4 o;
            o.x = f2bf(acc[r][0]); o.y = f2bf(acc[r][1]);
            o.z = f2bf(acc[r][2]); o.w = f2bf(acc[r][3]);
            *(ushort4*)(Gbf + (size_t)gr * FDIM + c0) = o;
        }
    }
}

// ---- k2: histogram, one thread per edge, 64B-padded global counters ----
__global__ __launch_bounds__(256) void k_hist(const int* __restrict__ idx, int E,
                                              int supRows, int nI1,
                                              unsigned* __restrict__ cnt16) {
    int e = blockIdx.x * 256 + threadIdx.x;
    if (e < E) {
        int i0 = idx[e];
        int i1 = idx[E + e];
        int b = (i0 / supRows) * nI1 + i1 / BROWS;
        atomicAdd(&cnt16[(size_t)b * 16], 1u);
    }
}

// ---- k3: single-block scan over nb (<=8192) padded counters.
// Writes bucketStart[0..nb] and rewrites cnt16 in place as cursors. ----
__global__ __launch_bounds__(256) void k_scan(unsigned* __restrict__ cnt16, int nb,
                                              unsigned* __restrict__ bucketStart) {
    __shared__ unsigned wS[4];
    int t = threadIdx.x;
    int per = (nb + 255) / 256;   // <=32
    unsigned local[32];
    unsigned s = 0;
    for (int i = 0; i < per; ++i) {
        int b = t * per + i;
        unsigned v = (b < nb) ? cnt16[(size_t)b * 16] : 0u;
        local[i] = s;
        s += v;
    }
    int lane = t & 63, wid = t >> 6;
    unsigned incl = s;
    for (int d = 1; d < 64; d <<= 1) {
        unsigned u = __shfl_up(incl, d, 64);
        if (lane >= d) incl += u;
    }
    if (lane == 63) wS[wid] = incl;
    __syncthreads();
    unsigned wOff = 0;
    for (int i = 0; i < wid; ++i) wOff += wS[i];
    unsigned base = wOff + incl - s;   // exclusive prefix of this thread
    for (int i = 0; i < per; ++i) {
        int b = t * per + i;
        if (b < nb) {
            unsigned st = base + local[i];
            bucketStart[b] = st;
            cnt16[(size_t)b * 16] = st;   // becomes cursor
        }
    }
    if (t == 255) bucketStart[nb] = base + s;   // = E
}

// ---- k4: scatter, one thread per edge, atomic cursor reservation ----
__global__ __launch_bounds__(256) void k_scatter(const int* __restrict__ idx,
                                                 const int* __restrict__ mol, int E,
                                                 int supRows, int nI1,
                                                 unsigned* __restrict__ cursor16,
                                                 unsigned* __restrict__ sortedE) {
    int e = blockIdx.x * 256 + threadIdx.x;
    if (e < E) {
        int i0 = idx[e];
        int i1 = idx[E + e];
        int m  = mol[e];
        int i1b = i1 / BROWS;
        int b = (i0 / supRows) * nI1 + i1b;
        int loc = i1 - i1b * BROWS;
        unsigned pos = atomicAdd(&cursor16[(size_t)b * 16], 1u);
        sortedE[pos] = (unsigned)i0 | ((unsigned)m << 16) | ((unsigned)loc << 26);
    }
}

// ---- k5: edge kernel. One WG per bucket: F window in LDS, gather only G.
// Bucket order (i0sup major) keeps the whole device inside one 3.2MB G slice
// at a time -> G gathers mostly hit per-XCD L2. ----
__global__ __launch_bounds__(256) void edge_kernel(
    const unsigned short* __restrict__ Gbf, const unsigned short* __restrict__ Fbf,
    const unsigned* __restrict__ sortedE, const unsigned* __restrict__ bucketStart,
    float* __restrict__ part, int nI1, int N) {
    __shared__ unsigned short sFrow[32 * FDIM];   // 8 KB

    int b = blockIdx.x;
    int i1b = b % nI1;
    int row0 = i1b * BROWS;
    int nrow = min(BROWS, N - row0);
    for (int k = threadIdx.x; k < nrow * (FDIM / 8); k += 256)
        ((uint4*)sFrow)[k] = ((const uint4*)(Fbf + (size_t)row0 * FDIM))[k];
    __syncthreads();

    int s = bucketStart[b];
    int e_end = bucketStart[b + 1];

    const int lane = threadIdx.x & 63;
    const int sub  = lane >> 4;
    const int t16  = lane & 15;
    const int wid  = threadIdx.x >> 6;
    float* pout = part + ((b & 31) << 10);

    for (int base = s + wid * 4; base < e_end; base += 16) {
        int e = base + sub;
        bool valid = (e < e_end);
        unsigned pk = valid ? sortedE[e] : 0u;
        int i0  = pk & 0xffff;
        int m   = (pk >> 16) & 0x3ff;
        int loc = pk >> 26;
        const uint4 g = *(const uint4*)(Gbf + (size_t)i0 * FDIM + t16 * 8);
        const uint4 f = *(const uint4*)(sFrow + loc * FDIM + t16 * 8);
        float p;
        p = bf_lo(g.x) * bf_lo(f.x);
        p = fmaf(bf_hi(g.x), bf_hi(f.x), p);
        p = fmaf(bf_lo(g.y), bf_lo(f.y), p);
        p = fmaf(bf_hi(g.y), bf_hi(f.y), p);
        p = fmaf(bf_lo(g.z), bf_lo(f.z), p);
        p = fmaf(bf_hi(g.z), bf_hi(f.z), p);
        p = fmaf(bf_lo(g.w), bf_lo(f.w), p);
        p = fmaf(bf_hi(g.w), bf_hi(f.w), p);
        p += __shfl_xor(p, 1, 16);
        p += __shfl_xor(p, 2, 16);
        p += __shfl_xor(p, 4, 16);
        p += __shfl_xor(p, 8, 16);
        if (t16 == 0 && valid) atomicAdd(pout + m, p);
    }
}

// ---- k6: reduce 32 partial copies -> out ----
__global__ __launch_bounds__(256) void k_red(const float* __restrict__ part,
                                             float* __restrict__ out, int M) {
    int m = blockIdx.x * 256 + threadIdx.x;
    if (m < M) {
        float s = 0.f;
        for (int c = 0; c < 32; ++c) s += part[(c << 10) + m];
        out[m] = s;
    }
}

extern "C" void kernel_launch(void* const* d_in, const int* in_sizes, int n_in,
                              void* d_out, int out_size, void* d_ws, size_t ws_size,
                              hipStream_t stream) {
    const float* Fm = (const float*)d_in[0];
    const float* W  = (const float*)d_in[1];
    const int* idx  = (const int*)d_in[2];
    const int* mol  = (const int*)d_in[3];
    float* out = (float*)d_out;

    const int N = in_sizes[0] / FDIM;   // 50000
    const int E = in_sizes[3];          // 1600000

    const int nI1     = (N + BROWS - 1) / BROWS;    // 2000
    const int supRows = (N + NSUP - 1) / NSUP;      // 12500
    const int nb      = NSUP * nI1;                 // 8000

    // workspace layout
    char* ws = (char*)d_ws;
    size_t o = 0;
    float* Ws = (float*)(ws + o);                    o += 64 * 1024;
    unsigned short* Fbf = (unsigned short*)(ws + o); o += ((size_t)N * FDIM * 2 + 255) & ~(size_t)255;
    unsigned short* Gbf = (unsigned short*)(ws + o); o += ((size_t)N * FDIM * 2 + 255) & ~(size_t)255;
    unsigned* sortedE = (unsigned*)(ws + o);         o += ((size_t)E * 4 + 255) & ~(size_t)255;
    unsigned* cnt16 = (unsigned*)(ws + o);           o += (size_t)nb * 64;
    unsigned* bucketStart = (unsigned*)(ws + o);     o += ((size_t)(nb + 1) * 4 + 255) & ~(size_t)255;
    float* part = (float*)(ws + o);                  o += 32 * 1024 * sizeof(float);

    hipMemsetAsync(cnt16, 0, (size_t)nb * 64, stream);
    hipMemsetAsync(part, 0, 32 * 1024 * sizeof(float), stream);

    make_ws<<<FDIM * FDIM / 256, 256, 0, stream>>>(W, Ws);
    gemm_g<<<(N + 31) / 32, 256, 0, stream>>>(Fm, Ws, Gbf, Fbf, N);

    int eBlocks = (E + 255) / 256;
    k_hist<<<eBlocks, 256, 0, stream>>>(idx, E, supRows, nI1, cnt16);
    k_scan<<<1, 256, 0, stream>>>(cnt16, nb, bucketStart);
    k_scatter<<<eBlocks, 256, 0, stream>>>(idx, mol, E, supRows, nI1, cnt16, sortedE);

    edge_kernel<<<nb, 256, 0, stream>>>(Gbf, Fbf, sortedE, bucketStart, part, nI1, N);

    k_red<<<(out_size + 255) / 256, 256, 0, stream>>>(part, out, out_size);
}